// Round 4
// baseline (1060.768 us; speedup 1.0000x reference)
//
#include <hip/hip_runtime.h>

#define NB 128
#define NS 256
#define NI 64
#define NH 128
#define NL 64
#define NG 384  // 3*NH

typedef _Float16 f16;
typedef __attribute__((ext_vector_type(2))) _Float16 f16x2;

__device__ __forceinline__ float fast_tanh(float x) {
    float e = __expf(2.0f * x);
    return 1.0f - 2.0f / (e + 1.0f);
}
__device__ __forceinline__ float fast_sig(float x) {
    return 1.0f / (1.0f + __expf(-x));
}
__device__ __forceinline__ float red2(float a) {
    a += __shfl_xor(a, 1);
    return a;
}
__device__ __forceinline__ float fdot2(f16x2 a, f16x2 b, float c) {
#if __has_builtin(__builtin_amdgcn_fdot2)
    return __builtin_amdgcn_fdot2(a, b, c, false);
#else
    return c + (float)a.x * (float)b.x + (float)a.y * (float)b.y;
#endif
}
__device__ __forceinline__ f16x2 bc16(unsigned int u) {
    return __builtin_bit_cast(f16x2, u);
}

// ---- f16 weight tables (pre-rounded once by prep_kernel) ----
__device__ __align__(16) f16 g_W1h[NH * NH];
__device__ __align__(16) f16 g_W2h[NH * NH];
__device__ __align__(16) f16 g_W12h[NH * NH];
__device__ __align__(16) f16 g_Whhh[3 * NH * NH];
__device__ __align__(16) f16 g_Whh2h[3 * NH * NH];
__device__ float g_w1b2[NH];
__device__ float g_whhb2[3 * NH];

// ---------------------------------------------------------------------------
// GX precompute: gx[s][b][j] = b_ih[j] + sum_c x[b][s][c] * W_ih[j][c]
// ---------------------------------------------------------------------------
__global__ __launch_bounds__(384)
void gx_kernel(const float* __restrict__ x, const float* __restrict__ W_ih,
               const float* __restrict__ b_ih, float* __restrict__ gx)
{
    const int s = blockIdx.x;
    const int j = threadIdx.x;
    __shared__ __align__(16) float xs[NB * NI];
    for (int idx = j; idx < NB * NI; idx += 384) {
        int bb = idx >> 6, cc = idx & 63;
        xs[idx] = x[(bb * NS + s) * NI + cc];
    }
    float w[64];
#pragma unroll
    for (int c = 0; c < 64; c += 4)
        *(float4*)&w[c] = *(const float4*)&W_ih[j * NI + c];
    const float bj = b_ih[j];
    __syncthreads();
    for (int bb = 0; bb < NB; bb++) {
        const float* xr = xs + bb * NI;
        float a0 = 0.f, a1 = 0.f, a2 = 0.f, a3 = 0.f;
#pragma unroll
        for (int c = 0; c < 64; c += 4) {
            a0 = fmaf(w[c + 0], xr[c + 0], a0);
            a1 = fmaf(w[c + 1], xr[c + 1], a1);
            a2 = fmaf(w[c + 2], xr[c + 2], a2);
            a3 = fmaf(w[c + 3], xr[c + 3], a3);
        }
        gx[((size_t)s * NB + bb) * NG + j] = ((a0 + a1) + (a2 + a3)) + bj;
    }
}

// ---------------------------------------------------------------------------
// Setup (fp32 math, then round to f16): W12=W1@W2, Whh2=Whh@W2, W1b2, Whhb2,
// plus f16 copies of W1, W2, Whh.
// ---------------------------------------------------------------------------
__global__ __launch_bounds__(128)
void prep_kernel(const float* __restrict__ W1, const float* __restrict__ Whh,
                 const float* __restrict__ W2, const float* __restrict__ b2)
{
    const int i = blockIdx.x;   // 0..511
    const int j = threadIdx.x;  // 0..127
    __shared__ float rowA[NH];
    __shared__ float red[NH];
    const float* src = (i < NH) ? (W1 + i * NH) : (Whh + (size_t)(i - NH) * NH);
    rowA[j] = src[j];
    __syncthreads();
    float acc = 0.f;
    for (int k = 0; k < NH; k++) acc = fmaf(rowA[k], W2[k * NH + j], acc);
    if (i < NH) {
        g_W12h[i * NH + j] = (f16)acc;
        g_W1h[i * NH + j]  = (f16)rowA[j];
        g_W2h[i * NH + j]  = (f16)W2[i * NH + j];
    } else {
        g_Whh2h[(size_t)(i - NH) * NH + j] = (f16)acc;
        g_Whhh[(size_t)(i - NH) * NH + j]  = (f16)rowA[j];
    }
    red[j] = rowA[j] * b2[j];
    __syncthreads();
    for (int off = 64; off > 0; off >>= 1) {
        if (j < off) red[j] += red[j + off];
        __syncthreads();
    }
    if (j == 0) {
        if (i < NH) g_w1b2[i] = red[0];
        else        g_whhb2[i - NH] = red[0];
    }
}

// ---------------------------------------------------------------------------
// dot helpers: 256 threads, 2 lanes per row. Lane p owns cols [64p, 64p+64)
// as 8 rotated 16B chunks (rotation by 4 chunks for p=1 -> disjoint banks).
// Weight arrays: f16x2[32] in registers, literal indices only.
// ---------------------------------------------------------------------------
#define CHNK(SRC, OB) (*(const uint4*)((const unsigned char*)(SRC) + (OB)))

#define D4(W, K, V, A0, A1)                                                    \
    A0 = fdot2(W[K + 0], bc16((V).x), A0);                                     \
    A1 = fdot2(W[K + 1], bc16((V).y), A1);                                     \
    A0 = fdot2(W[K + 2], bc16((V).z), A0);                                     \
    A1 = fdot2(W[K + 3], bc16((V).w), A1);

#define DOT1(W, SRC, OUT)                                                      \
    {                                                                          \
        float a0_ = 0.f, a1_ = 0.f;                                            \
        { uint4 v_ = CHNK(SRC, ob0); D4(W, 0,  v_, a0_, a1_) }                 \
        { uint4 v_ = CHNK(SRC, ob1); D4(W, 4,  v_, a0_, a1_) }                 \
        { uint4 v_ = CHNK(SRC, ob2); D4(W, 8,  v_, a0_, a1_) }                 \
        { uint4 v_ = CHNK(SRC, ob3); D4(W, 12, v_, a0_, a1_) }                 \
        { uint4 v_ = CHNK(SRC, ob4); D4(W, 16, v_, a0_, a1_) }                 \
        { uint4 v_ = CHNK(SRC, ob5); D4(W, 20, v_, a0_, a1_) }                 \
        { uint4 v_ = CHNK(SRC, ob6); D4(W, 24, v_, a0_, a1_) }                 \
        { uint4 v_ = CHNK(SRC, ob7); D4(W, 28, v_, a0_, a1_) }                 \
        OUT = red2(a0_ + a1_);                                                 \
    }

#define DOT2S(WA, WB, SRC, OA, OB)                                             \
    {                                                                          \
        float a0_ = 0.f, a1_ = 0.f, b0_ = 0.f, b1_ = 0.f;                      \
        { uint4 v_ = CHNK(SRC, ob0); D4(WA, 0,  v_, a0_, a1_) D4(WB, 0,  v_, b0_, b1_) } \
        { uint4 v_ = CHNK(SRC, ob1); D4(WA, 4,  v_, a0_, a1_) D4(WB, 4,  v_, b0_, b1_) } \
        { uint4 v_ = CHNK(SRC, ob2); D4(WA, 8,  v_, a0_, a1_) D4(WB, 8,  v_, b0_, b1_) } \
        { uint4 v_ = CHNK(SRC, ob3); D4(WA, 12, v_, a0_, a1_) D4(WB, 12, v_, b0_, b1_) } \
        { uint4 v_ = CHNK(SRC, ob4); D4(WA, 16, v_, a0_, a1_) D4(WB, 16, v_, b0_, b1_) } \
        { uint4 v_ = CHNK(SRC, ob5); D4(WA, 20, v_, a0_, a1_) D4(WB, 20, v_, b0_, b1_) } \
        { uint4 v_ = CHNK(SRC, ob6); D4(WA, 24, v_, a0_, a1_) D4(WB, 24, v_, b0_, b1_) } \
        { uint4 v_ = CHNK(SRC, ob7); D4(WA, 28, v_, a0_, a1_) D4(WB, 28, v_, b0_, b1_) } \
        OA = red2(a0_ + a1_);                                                  \
        OB = red2(b0_ + b1_);                                                  \
    }

#define DOT2D(WA, SA, WB, SB, OA, OB)                                          \
    {                                                                          \
        float a0_ = 0.f, a1_ = 0.f, b0_ = 0.f, b1_ = 0.f;                      \
        { uint4 v_ = CHNK(SA, ob0); uint4 u_ = CHNK(SB, ob0); D4(WA, 0,  v_, a0_, a1_) D4(WB, 0,  u_, b0_, b1_) } \
        { uint4 v_ = CHNK(SA, ob1); uint4 u_ = CHNK(SB, ob1); D4(WA, 4,  v_, a0_, a1_) D4(WB, 4,  u_, b0_, b1_) } \
        { uint4 v_ = CHNK(SA, ob2); uint4 u_ = CHNK(SB, ob2); D4(WA, 8,  v_, a0_, a1_) D4(WB, 8,  u_, b0_, b1_) } \
        { uint4 v_ = CHNK(SA, ob3); uint4 u_ = CHNK(SB, ob3); D4(WA, 12, v_, a0_, a1_) D4(WB, 12, u_, b0_, b1_) } \
        { uint4 v_ = CHNK(SA, ob4); uint4 u_ = CHNK(SB, ob4); D4(WA, 16, v_, a0_, a1_) D4(WB, 16, u_, b0_, b1_) } \
        { uint4 v_ = CHNK(SA, ob5); uint4 u_ = CHNK(SB, ob5); D4(WA, 20, v_, a0_, a1_) D4(WB, 20, u_, b0_, b1_) } \
        { uint4 v_ = CHNK(SA, ob6); uint4 u_ = CHNK(SB, ob6); D4(WA, 24, v_, a0_, a1_) D4(WB, 24, u_, b0_, b1_) } \
        { uint4 v_ = CHNK(SA, ob7); uint4 u_ = CHNK(SB, ob7); D4(WA, 28, v_, a0_, a1_) D4(WB, 28, u_, b0_, b1_) } \
        OA = red2(a0_ + a1_);                                                  \
        OB = red2(b0_ + b1_);                                                  \
    }

#define DOT4S(WA, WB, WC, WD, SRC, OA, OB, OC, OD)                             \
    {                                                                          \
        float a0_ = 0.f, a1_ = 0.f, b0_ = 0.f, b1_ = 0.f;                      \
        float c0_ = 0.f, c1_ = 0.f, d0_ = 0.f, d1_ = 0.f;                      \
        { uint4 v_ = CHNK(SRC, ob0); D4(WA, 0,  v_, a0_, a1_) D4(WB, 0,  v_, b0_, b1_) D4(WC, 0,  v_, c0_, c1_) D4(WD, 0,  v_, d0_, d1_) } \
        { uint4 v_ = CHNK(SRC, ob1); D4(WA, 4,  v_, a0_, a1_) D4(WB, 4,  v_, b0_, b1_) D4(WC, 4,  v_, c0_, c1_) D4(WD, 4,  v_, d0_, d1_) } \
        { uint4 v_ = CHNK(SRC, ob2); D4(WA, 8,  v_, a0_, a1_) D4(WB, 8,  v_, b0_, b1_) D4(WC, 8,  v_, c0_, c1_) D4(WD, 8,  v_, d0_, d1_) } \
        { uint4 v_ = CHNK(SRC, ob3); D4(WA, 12, v_, a0_, a1_) D4(WB, 12, v_, b0_, b1_) D4(WC, 12, v_, c0_, c1_) D4(WD, 12, v_, d0_, d1_) } \
        { uint4 v_ = CHNK(SRC, ob4); D4(WA, 16, v_, a0_, a1_) D4(WB, 16, v_, b0_, b1_) D4(WC, 16, v_, c0_, c1_) D4(WD, 16, v_, d0_, d1_) } \
        { uint4 v_ = CHNK(SRC, ob5); D4(WA, 20, v_, a0_, a1_) D4(WB, 20, v_, b0_, b1_) D4(WC, 20, v_, c0_, c1_) D4(WD, 20, v_, d0_, d1_) } \
        { uint4 v_ = CHNK(SRC, ob6); D4(WA, 24, v_, a0_, a1_) D4(WB, 24, v_, b0_, b1_) D4(WC, 24, v_, c0_, c1_) D4(WD, 24, v_, d0_, d1_) } \
        { uint4 v_ = CHNK(SRC, ob7); D4(WA, 28, v_, a0_, a1_) D4(WB, 28, v_, b0_, b1_) D4(WC, 28, v_, c0_, c1_) D4(WD, 28, v_, d0_, d1_) } \
        OA = red2(a0_ + a1_);                                                  \
        OB = red2(b0_ + b1_);                                                  \
        OC = red2(c0_ + c1_);                                                  \
        OD = red2(d0_ + d1_);                                                  \
    }

#define LDCH(DST, K, BP, OB)                                                   \
    {                                                                          \
        uint4 v_ = *(const uint4*)((BP) + (OB));                               \
        DST[K + 0] = bc16(v_.x); DST[K + 1] = bc16(v_.y);                      \
        DST[K + 2] = bc16(v_.z); DST[K + 3] = bc16(v_.w);                      \
    }

#define LOADW(DST, BASE)                                                       \
    {                                                                          \
        const unsigned char* bp_ = (const unsigned char*)(BASE);               \
        LDCH(DST, 0,  bp_, ob0) LDCH(DST, 4,  bp_, ob1)                        \
        LDCH(DST, 8,  bp_, ob2) LDCH(DST, 12, bp_, ob3)                        \
        LDCH(DST, 16, bp_, ob4) LDCH(DST, 20, bp_, ob5)                        \
        LDCH(DST, 24, bp_, ob6) LDCH(DST, 28, bp_, ob7)                        \
    }

// ---------------------------------------------------------------------------
// Main recurrence: 1 WG / batch element, 256 threads (2 lanes per row),
// 4 waves (1 per SIMD), 9 serial stages / step, all 9 weight matrices
// genuinely register-resident as packed f16 (288 VGPRs, budget 512).
// ---------------------------------------------------------------------------
__global__ __launch_bounds__(256, 1)
void rnn_kernel(const float* __restrict__ times, const float* __restrict__ b_hh,
                const float* __restrict__ b1, const float* __restrict__ b2,
                const float* __restrict__ W_mean, const float* __restrict__ b_mean,
                const float* __restrict__ W_logvar, const float* __restrict__ b_logvar,
                const float* __restrict__ gx,
                const float* __restrict__ x, const float* __restrict__ W_ih,
                const float* __restrict__ b_ih,
                const int use_gx,
                float* __restrict__ out)
{
    const int b = blockIdx.x;
    const int t = threadIdx.x;    // 0..255
    const int r = t >> 1;         // row 0..127
    const int p = t & 1;          // half 0/1

    __shared__ __align__(16) f16 shHh[NH], shUh[NH], shAh[NH];
    __shared__ float shT[NS];
    __shared__ __align__(16) float shGX[NG], shX[NI], shHf[NH];

    // rotated chunk byte offsets: lane p owns cols [64p,64p+64); chunk order
    // rotated by 4 for p=1 so the two lanes' reads hit disjoint bank groups.
    const int ob0 = 128 * p + 16 * ((0 + 4 * p) & 7);
    const int ob1 = 128 * p + 16 * ((1 + 4 * p) & 7);
    const int ob2 = 128 * p + 16 * ((2 + 4 * p) & 7);
    const int ob3 = 128 * p + 16 * ((3 + 4 * p) & 7);
    const int ob4 = 128 * p + 16 * ((4 + 4 * p) & 7);
    const int ob5 = 128 * p + 16 * ((5 + 4 * p) & 7);
    const int ob6 = 128 * p + 16 * ((6 + 4 * p) & 7);
    const int ob7 = 128 * p + 16 * ((7 + 4 * p) & 7);

    // ---- register-resident packed-f16 weights (literal indices only) ----
    f16x2 w1p[32], w2p[32], w12p[32];
    f16x2 wh0p[32], wh1p[32], wh2p[32];
    f16x2 ws0p[32], ws1p[32], ws2p[32];
    LOADW(w1p,  g_W1h  + r * NH);
    LOADW(w2p,  g_W2h  + r * NH);
    LOADW(w12p, g_W12h + r * NH);
    LOADW(wh0p, g_Whhh + (0 * NH + r) * NH);
    LOADW(wh1p, g_Whhh + (1 * NH + r) * NH);
    LOADW(wh2p, g_Whhh + (2 * NH + r) * NH);
    LOADW(ws0p, g_Whh2h + (size_t)(0 * NH + r) * NH);
    LOADW(ws1p, g_Whh2h + (size_t)(1 * NH + r) * NH);
    LOADW(ws2p, g_Whh2h + (size_t)(2 * NH + r) * NH);

    const float b1r = b1[r], b2r = b2[r];
    const float bh0 = b_hh[r], bh1 = b_hh[NH + r], bh2 = b_hh[2 * NH + r];
    const float w1b2r = g_w1b2[r];
    const float wb0 = g_whhb2[r], wb1 = g_whhb2[NH + r], wb2 = g_whhb2[2 * NH + r];

    if (t < NS) shT[t] = times[t];
    if (t < NH) shHh[t] = (f16)0.f;
    float h = 0.f;  // fp32 h carried in registers (both lanes of the pair)
    __syncthreads();

    // gx double-buffer: load step si's values one iteration ahead.
    float gxr = 0.f, gxz = 0.f, gxn = 0.f;
    if (use_gx) {
        const float* g = gx + ((size_t)(NS - 1) * NB + b) * NG;
        gxr = g[r]; gxz = g[NH + r]; gxn = g[2 * NH + r];
    }

    for (int si = 0; si < NS; ++si) {
        const int seq = NS - 1 - si;
        const float dt = (si == 0) ? 0.f : (shT[seq] - shT[seq + 1]);
        const float dts = 0.5f * dt;  // substep dt (N_SUB=2)
        const float a2 = 0.5f * dts;
        const float a6 = dts * (1.f / 6.f);

        // issue NEXT step's gx loads now; consumed next iteration (latency
        // hidden under this step's 9 stages).
        float gnr = 0.f, gnz = 0.f, gnn = 0.f;
        if (use_gx) {
            const int seqn = (seq > 0) ? (seq - 1) : 0;
            const float* g = gx + ((size_t)seqn * NB + b) * NG;
            gnr = g[r]; gnz = g[NH + r]; gnn = g[2 * NH + r];
        } else {
            if (t < NI) shX[t] = x[(b * NS + seq) * NI + t];
            __syncthreads();
            for (int idx = t; idx < NG; idx += 256) {
                const float* wr = W_ih + idx * NI;
                float a = 0.f;
#pragma unroll
                for (int cc = 0; cc < NI; cc += 4) {
                    float4 w4 = *(const float4*)(wr + cc);
                    a = fmaf(w4.x, shX[cc + 0], a);
                    a = fmaf(w4.y, shX[cc + 1], a);
                    a = fmaf(w4.z, shX[cc + 2], a);
                    a = fmaf(w4.w, shX[cc + 3], a);
                }
                shGX[idx] = a + b_ih[idx];
            }
            __syncthreads();
        }

        // ======== substep A ========
        float z1a, u, S, m;
        // stage 1: z1 = W1 h + b1
        DOT1(w1p, shHh, z1a);
        z1a += b1r;
        u = fast_tanh(z1a);
        S = u;
        if (p == 0) shUh[r] = (f16)u;
        __syncthreads();
        // stage 2
        DOT1(w12p, shUh, m);
        u = fast_tanh(z1a + a2 * (m + w1b2r));
        S += 2.f * u;
        if (p == 0) shUh[r] = (f16)u;
        __syncthreads();
        // stage 3
        DOT1(w12p, shUh, m);
        u = fast_tanh(z1a + a2 * (m + w1b2r));
        S += 2.f * u;
        if (p == 0) shUh[r] = (f16)u;
        __syncthreads();
        // stage 4 (k4 uses full dts)
        DOT1(w12p, shUh, m);
        u = fast_tanh(z1a + dts * (m + w1b2r));
        S += u;
        if (p == 0) shUh[r] = (f16)S;  // S becomes the stage-5 source
        __syncthreads();
        // stage 5: hA = h + a6 W2 S + dts b2 ; z1b = z1a + a6 W12 S + dts W1b2
        float mA, mB;
        DOT2S(w2p, w12p, shUh, mA, mB);
        const float hA = h + a6 * mA + dts * b2r;
        const float z1b = z1a + a6 * mB + dts * w1b2r;
        u = fast_tanh(z1b);
        float S2 = u;
        if (p == 0) { shAh[r] = (f16)hA; shUh[r] = (f16)u; }
        __syncthreads();

        // ======== substep B (+ Whh·hA folded in as pair-matvecs) ========
        float g0, g1, g2;
        // stage 6
        DOT2D(w12p, shUh, wh0p, shAh, m, g0);
        u = fast_tanh(z1b + a2 * (m + w1b2r));
        S2 += 2.f * u;
        if (p == 0) shUh[r] = (f16)u;
        __syncthreads();
        // stage 7
        DOT2D(w12p, shUh, wh1p, shAh, m, g1);
        u = fast_tanh(z1b + a2 * (m + w1b2r));
        S2 += 2.f * u;
        if (p == 0) shUh[r] = (f16)u;
        __syncthreads();
        // stage 8
        DOT2D(w12p, shUh, wh2p, shAh, m, g2);
        u = fast_tanh(z1b + dts * (m + w1b2r));
        S2 += u;
        if (p == 0) shUh[r] = (f16)S2;  // S2 becomes the stage-9 source
        __syncthreads();
        // stage 9: quad matvec over S2 ; GRU (computed on both lanes)
        float n0, n1, n2, n3;
        DOT4S(w2p, ws0p, ws1p, ws2p, shUh, n0, n1, n2, n3);
        const float hB = hA + a6 * n0 + dts * b2r;
        const float rh = g0 + a6 * n1 + dts * wb0 + bh0;
        const float zh = g1 + a6 * n2 + dts * wb1 + bh1;
        const float nh = g2 + a6 * n3 + dts * wb2 + bh2;
        float rx, zx, nx;
        if (use_gx) { rx = gxr; zx = gxz; nx = gxn; }
        else        { rx = shGX[r]; zx = shGX[NH + r]; nx = shGX[2 * NH + r]; }
        const float rr = fast_sig(rx + rh);
        const float zz = fast_sig(zx + zh);
        const float nn = fast_tanh(nx + rr * nh);
        h = (1.f - zz) * nn + zz * hB;
        if (p == 0) shHh[r] = (f16)h;
        // rotate gx double-buffer
        gxr = gnr; gxz = gnz; gxn = gnn;
        __syncthreads();
    }

    // ---- epilogue: full-precision heads from fp32 h ----
    if (p == 0) shHf[r] = h;
    __syncthreads();
    const int sel = r >> 6;
    const int l = r & 63;
    const float* Wf = sel ? W_logvar : W_mean;
    const int hc0 = 64 * p;
    float a0 = 0.f, a1 = 0.f;
#pragma unroll
    for (int jj = 0; jj < 16; jj++) {
        float4 w4 = *(const float4*)&Wf[l * NH + hc0 + 4 * jj];
        float4 h4 = *(const float4*)(shHf + hc0 + 4 * jj);
        a0 = fmaf(w4.x, h4.x, a0);
        a1 = fmaf(w4.y, h4.y, a1);
        a0 = fmaf(w4.z, h4.z, a0);
        a1 = fmaf(w4.w, h4.w, a1);
    }
    float acc = red2(a0 + a1);
    if (p == 0) {
        const float bias = sel ? b_logvar[l] : b_mean[l];
        out[sel * (NB * NL) + b * NL + l] = acc + bias;
    }
}

extern "C" void kernel_launch(void* const* d_in, const int* in_sizes, int n_in,
                              void* d_out, int out_size, void* d_ws, size_t ws_size,
                              hipStream_t stream)
{
    const float* x        = (const float*)d_in[0];
    const float* times    = (const float*)d_in[1];
    const float* W_ih     = (const float*)d_in[2];
    const float* W_hh     = (const float*)d_in[3];
    const float* b_ih     = (const float*)d_in[4];
    const float* b_hh     = (const float*)d_in[5];
    const float* W1       = (const float*)d_in[6];
    const float* b1       = (const float*)d_in[7];
    const float* W2       = (const float*)d_in[8];
    const float* b2       = (const float*)d_in[9];
    const float* W_mean   = (const float*)d_in[10];
    const float* b_mean   = (const float*)d_in[11];
    const float* W_logvar = (const float*)d_in[12];
    const float* b_logvar = (const float*)d_in[13];
    float* out = (float*)d_out;

    float* gxbuf = (float*)d_ws;
    const size_t need = (size_t)NS * NB * NG * sizeof(float);  // ~50.3 MB
    const int use_gx = (d_ws != nullptr && ws_size >= need) ? 1 : 0;

    if (use_gx) {
        gx_kernel<<<NS, 384, 0, stream>>>(x, W_ih, b_ih, gxbuf);
    }
    prep_kernel<<<512, 128, 0, stream>>>(W1, W_hh, W2, b2);
    rnn_kernel<<<NB, 256, 0, stream>>>(times, b_hh, b1, b2,
                                       W_mean, b_mean, W_logvar, b_logvar,
                                       gxbuf, x, W_ih, b_ih, use_gx, out);
}

// Round 5
// 912.073 us; speedup vs baseline: 1.1630x; 1.1630x over previous
//
#include <hip/hip_runtime.h>

#define NB 128
#define NS 256
#define NI 64
#define NH 128
#define NL 64
#define NG 384  // 3*NH

typedef _Float16 f16;
typedef __attribute__((ext_vector_type(2))) _Float16 f16x2;

__device__ __forceinline__ float fast_tanh(float x) {
    float e = __expf(2.0f * x);
    return 1.0f - 2.0f / (e + 1.0f);
}
__device__ __forceinline__ float fast_sig(float x) {
    return 1.0f / (1.0f + __expf(-x));
}
// quad reduce via DPP (pure VALU, no LDS pipe)
template <int CTRL>
__device__ __forceinline__ float dpp_xor_add(float a) {
    int ai = __builtin_bit_cast(int, a);
    int bi = __builtin_amdgcn_update_dpp(0, ai, CTRL, 0xF, 0xF, true);
    return a + __builtin_bit_cast(float, bi);
}
__device__ __forceinline__ float quad_red(float a) {
    a = dpp_xor_add<0xB1>(a);  // quad_perm [1,0,3,2]  (xor 1)
    a = dpp_xor_add<0x4E>(a);  // quad_perm [2,3,0,1]  (xor 2)
    return a;
}
__device__ __forceinline__ float fdot2(f16x2 a, f16x2 b, float c) {
#if __has_builtin(__builtin_amdgcn_fdot2)
    return __builtin_amdgcn_fdot2(a, b, c, false);
#else
    return c + (float)a.x * (float)b.x + (float)a.y * (float)b.y;
#endif
}
__device__ __forceinline__ f16x2 bc16(unsigned int u) {
    return __builtin_bit_cast(f16x2, u);
}
// LDS-only workgroup barrier: does NOT drain vmcnt (global prefetch stays
// in flight). Write->sync->read pattern: lgkmcnt(0) commits my ds_write,
// s_barrier orders across waves, memory clobbers pin LDS ops.
__device__ __forceinline__ void sync_lds() {
    asm volatile("s_waitcnt lgkmcnt(0)" ::: "memory");
    __builtin_amdgcn_s_barrier();
    asm volatile("" ::: "memory");
}

// ---- f16 weight tables (pre-rounded once by prep_kernel) ----
__device__ __align__(16) f16 g_W1h[NH * NH];
__device__ __align__(16) f16 g_W2h[NH * NH];
__device__ __align__(16) f16 g_W12h[NH * NH];
__device__ __align__(16) f16 g_Whhh[3 * NH * NH];
__device__ __align__(16) f16 g_Whh2h[3 * NH * NH];
__device__ float g_w1b2[NH];
__device__ float g_whhb2[3 * NH];

// ---------------------------------------------------------------------------
// GX precompute: gx[s][b][j] = b_ih[j] + sum_c x[b][s][c] * W_ih[j][c]
// ---------------------------------------------------------------------------
__global__ __launch_bounds__(384)
void gx_kernel(const float* __restrict__ x, const float* __restrict__ W_ih,
               const float* __restrict__ b_ih, float* __restrict__ gx)
{
    const int s = blockIdx.x;
    const int j = threadIdx.x;
    __shared__ __align__(16) float xs[NB * NI];
    for (int idx = j; idx < NB * NI; idx += 384) {
        int bb = idx >> 6, cc = idx & 63;
        xs[idx] = x[(bb * NS + s) * NI + cc];
    }
    float w[64];
#pragma unroll
    for (int c = 0; c < 64; c += 4)
        *(float4*)&w[c] = *(const float4*)&W_ih[j * NI + c];
    const float bj = b_ih[j];
    __syncthreads();
    for (int bb = 0; bb < NB; bb++) {
        const float* xr = xs + bb * NI;
        float a0 = 0.f, a1 = 0.f, a2 = 0.f, a3 = 0.f;
#pragma unroll
        for (int c = 0; c < 64; c += 4) {
            a0 = fmaf(w[c + 0], xr[c + 0], a0);
            a1 = fmaf(w[c + 1], xr[c + 1], a1);
            a2 = fmaf(w[c + 2], xr[c + 2], a2);
            a3 = fmaf(w[c + 3], xr[c + 3], a3);
        }
        gx[((size_t)s * NB + bb) * NG + j] = ((a0 + a1) + (a2 + a3)) + bj;
    }
}

// ---------------------------------------------------------------------------
// Setup (fp32 math, then round to f16): W12=W1@W2, Whh2=Whh@W2, W1b2, Whhb2,
// plus f16 copies of W1, W2, Whh.
// ---------------------------------------------------------------------------
__global__ __launch_bounds__(128)
void prep_kernel(const float* __restrict__ W1, const float* __restrict__ Whh,
                 const float* __restrict__ W2, const float* __restrict__ b2)
{
    const int i = blockIdx.x;   // 0..511
    const int j = threadIdx.x;  // 0..127
    __shared__ float rowA[NH];
    __shared__ float red[NH];
    const float* src = (i < NH) ? (W1 + i * NH) : (Whh + (size_t)(i - NH) * NH);
    rowA[j] = src[j];
    __syncthreads();
    float acc = 0.f;
    for (int k = 0; k < NH; k++) acc = fmaf(rowA[k], W2[k * NH + j], acc);
    if (i < NH) {
        g_W12h[i * NH + j] = (f16)acc;
        g_W1h[i * NH + j]  = (f16)rowA[j];
        g_W2h[i * NH + j]  = (f16)W2[i * NH + j];
    } else {
        g_Whh2h[(size_t)(i - NH) * NH + j] = (f16)acc;
        g_Whhh[(size_t)(i - NH) * NH + j]  = (f16)rowA[j];
    }
    red[j] = rowA[j] * b2[j];
    __syncthreads();
    for (int off = 64; off > 0; off >>= 1) {
        if (j < off) red[j] += red[j + off];
        __syncthreads();
    }
    if (j == 0) {
        if (i < NH) g_w1b2[i] = red[0];
        else        g_whhb2[i - NH] = red[0];
    }
}

// ---------------------------------------------------------------------------
// dot helpers: 512 threads, 4 lanes per row. Quad lane p owns cols
// [32p, 32p+32) as 4 rotated 16B chunks (disjoint bank groups per quad).
// Weights: f16x2[16] per matrix in registers, literal indices only.
// ---------------------------------------------------------------------------
#define CHNK(SRC, OB) (*(const uint4*)((const unsigned char*)(SRC) + (OB)))

// 4 independent accumulator chains per weight (depth 1 per chunk)
#define D4(W, K, V, A0, A1, A2, A3)                                            \
    A0 = fdot2(W[K + 0], bc16((V).x), A0);                                     \
    A1 = fdot2(W[K + 1], bc16((V).y), A1);                                     \
    A2 = fdot2(W[K + 2], bc16((V).z), A2);                                     \
    A3 = fdot2(W[K + 3], bc16((V).w), A3);

// 2 chains per weight (for the 4-weight dot)
#define D2(W, K, V, A0, A1)                                                    \
    A0 = fdot2(W[K + 0], bc16((V).x), A0);                                     \
    A1 = fdot2(W[K + 1], bc16((V).y), A1);                                     \
    A0 = fdot2(W[K + 2], bc16((V).z), A0);                                     \
    A1 = fdot2(W[K + 3], bc16((V).w), A1);

#define DOT1(W, SRC, OUT)                                                      \
    {                                                                          \
        float a0_ = 0.f, a1_ = 0.f, a2_ = 0.f, a3_ = 0.f;                      \
        { uint4 v_ = CHNK(SRC, ob0); D4(W, 0,  v_, a0_, a1_, a2_, a3_) }       \
        { uint4 v_ = CHNK(SRC, ob1); D4(W, 4,  v_, a0_, a1_, a2_, a3_) }       \
        { uint4 v_ = CHNK(SRC, ob2); D4(W, 8,  v_, a0_, a1_, a2_, a3_) }       \
        { uint4 v_ = CHNK(SRC, ob3); D4(W, 12, v_, a0_, a1_, a2_, a3_) }       \
        OUT = quad_red((a0_ + a1_) + (a2_ + a3_));                             \
    }

#define DOT2S(WA, WB, SRC, OA, OB)                                             \
    {                                                                          \
        float a0_ = 0.f, a1_ = 0.f, a2_ = 0.f, a3_ = 0.f;                      \
        float b0_ = 0.f, b1_ = 0.f, b2_ = 0.f, b3_ = 0.f;                      \
        { uint4 v_ = CHNK(SRC, ob0); D4(WA, 0,  v_, a0_, a1_, a2_, a3_) D4(WB, 0,  v_, b0_, b1_, b2_, b3_) } \
        { uint4 v_ = CHNK(SRC, ob1); D4(WA, 4,  v_, a0_, a1_, a2_, a3_) D4(WB, 4,  v_, b0_, b1_, b2_, b3_) } \
        { uint4 v_ = CHNK(SRC, ob2); D4(WA, 8,  v_, a0_, a1_, a2_, a3_) D4(WB, 8,  v_, b0_, b1_, b2_, b3_) } \
        { uint4 v_ = CHNK(SRC, ob3); D4(WA, 12, v_, a0_, a1_, a2_, a3_) D4(WB, 12, v_, b0_, b1_, b2_, b3_) } \
        OA = quad_red((a0_ + a1_) + (a2_ + a3_));                              \
        OB = quad_red((b0_ + b1_) + (b2_ + b3_));                              \
    }

#define DOT2D(WA, SA, WB, SB, OA, OB)                                          \
    {                                                                          \
        float a0_ = 0.f, a1_ = 0.f, a2_ = 0.f, a3_ = 0.f;                      \
        float b0_ = 0.f, b1_ = 0.f, b2_ = 0.f, b3_ = 0.f;                      \
        { uint4 v_ = CHNK(SA, ob0); uint4 u_ = CHNK(SB, ob0); D4(WA, 0,  v_, a0_, a1_, a2_, a3_) D4(WB, 0,  u_, b0_, b1_, b2_, b3_) } \
        { uint4 v_ = CHNK(SA, ob1); uint4 u_ = CHNK(SB, ob1); D4(WA, 4,  v_, a0_, a1_, a2_, a3_) D4(WB, 4,  u_, b0_, b1_, b2_, b3_) } \
        { uint4 v_ = CHNK(SA, ob2); uint4 u_ = CHNK(SB, ob2); D4(WA, 8,  v_, a0_, a1_, a2_, a3_) D4(WB, 8,  u_, b0_, b1_, b2_, b3_) } \
        { uint4 v_ = CHNK(SA, ob3); uint4 u_ = CHNK(SB, ob3); D4(WA, 12, v_, a0_, a1_, a2_, a3_) D4(WB, 12, u_, b0_, b1_, b2_, b3_) } \
        OA = quad_red((a0_ + a1_) + (a2_ + a3_));                              \
        OB = quad_red((b0_ + b1_) + (b2_ + b3_));                              \
    }

#define DOT4S(WA, WB, WC, WD, SRC, OA, OB, OC, OD)                             \
    {                                                                          \
        float a0_ = 0.f, a1_ = 0.f, b0_ = 0.f, b1_ = 0.f;                      \
        float c0_ = 0.f, c1_ = 0.f, d0_ = 0.f, d1_ = 0.f;                      \
        { uint4 v_ = CHNK(SRC, ob0); D2(WA, 0,  v_, a0_, a1_) D2(WB, 0,  v_, b0_, b1_) D2(WC, 0,  v_, c0_, c1_) D2(WD, 0,  v_, d0_, d1_) } \
        { uint4 v_ = CHNK(SRC, ob1); D2(WA, 4,  v_, a0_, a1_) D2(WB, 4,  v_, b0_, b1_) D2(WC, 4,  v_, c0_, c1_) D2(WD, 4,  v_, d0_, d1_) } \
        { uint4 v_ = CHNK(SRC, ob2); D2(WA, 8,  v_, a0_, a1_) D2(WB, 8,  v_, b0_, b1_) D2(WC, 8,  v_, c0_, c1_) D2(WD, 8,  v_, d0_, d1_) } \
        { uint4 v_ = CHNK(SRC, ob3); D2(WA, 12, v_, a0_, a1_) D2(WB, 12, v_, b0_, b1_) D2(WC, 12, v_, c0_, c1_) D2(WD, 12, v_, d0_, d1_) } \
        OA = quad_red(a0_ + a1_);                                              \
        OB = quad_red(b0_ + b1_);                                              \
        OC = quad_red(c0_ + c1_);                                              \
        OD = quad_red(d0_ + d1_);                                              \
    }

#define LDCH(DST, K, BP, OB)                                                   \
    {                                                                          \
        uint4 v_ = *(const uint4*)((BP) + (OB));                               \
        DST[K + 0] = bc16(v_.x); DST[K + 1] = bc16(v_.y);                      \
        DST[K + 2] = bc16(v_.z); DST[K + 3] = bc16(v_.w);                      \
    }

#define LOADW(DST, BASE)                                                       \
    {                                                                          \
        const unsigned char* bp_ = (const unsigned char*)(BASE);               \
        LDCH(DST, 0, bp_, ob0) LDCH(DST, 4, bp_, ob1)                          \
        LDCH(DST, 8, bp_, ob2) LDCH(DST, 12, bp_, ob3)                         \
    }

// ---------------------------------------------------------------------------
// Main recurrence: 1 WG / batch element, 512 threads (4 lanes per row),
// 8 waves (2/SIMD), 9 serial stages / step. Weights 9 x 16 f16x2 = 144 VGPR.
// ---------------------------------------------------------------------------
__global__ __launch_bounds__(512, 2)
void rnn_kernel(const float* __restrict__ times, const float* __restrict__ b_hh,
                const float* __restrict__ b1, const float* __restrict__ b2,
                const float* __restrict__ W_mean, const float* __restrict__ b_mean,
                const float* __restrict__ W_logvar, const float* __restrict__ b_logvar,
                const float* __restrict__ gx,
                const float* __restrict__ x, const float* __restrict__ W_ih,
                const float* __restrict__ b_ih,
                const int use_gx,
                float* __restrict__ out)
{
    const int b = blockIdx.x;
    const int t = threadIdx.x;    // 0..511
    const int r = t >> 2;         // row 0..127
    const int p = t & 3;          // quad lane

    __shared__ __align__(16) f16 shHh[NH], shUh[NH], shAh[NH];
    __shared__ float shT[NS];
    __shared__ __align__(16) float shGX[NG], shX[NI], shHf[NH];

    // rotated chunk byte offsets: quad lane p owns bytes [64p, 64p+64) of the
    // 256B row; chunk order rotated by p so quads hit disjoint bank groups.
    const int ob0 = 64 * p + 16 * ((0 + p) & 3);
    const int ob1 = 64 * p + 16 * ((1 + p) & 3);
    const int ob2 = 64 * p + 16 * ((2 + p) & 3);
    const int ob3 = 64 * p + 16 * ((3 + p) & 3);

    // ---- register-resident packed-f16 weights (literal indices only) ----
    f16x2 w1p[16], w2p[16], w12p[16];
    f16x2 wh0p[16], wh1p[16], wh2p[16];
    f16x2 ws0p[16], ws1p[16], ws2p[16];
    LOADW(w1p,  g_W1h  + r * NH);
    LOADW(w2p,  g_W2h  + r * NH);
    LOADW(w12p, g_W12h + r * NH);
    LOADW(wh0p, g_Whhh + (0 * NH + r) * NH);
    LOADW(wh1p, g_Whhh + (1 * NH + r) * NH);
    LOADW(wh2p, g_Whhh + (2 * NH + r) * NH);
    LOADW(ws0p, g_Whh2h + (size_t)(0 * NH + r) * NH);
    LOADW(ws1p, g_Whh2h + (size_t)(1 * NH + r) * NH);
    LOADW(ws2p, g_Whh2h + (size_t)(2 * NH + r) * NH);

    const float b1r = b1[r], b2r = b2[r];
    const float bh0 = b_hh[r], bh1 = b_hh[NH + r], bh2 = b_hh[2 * NH + r];
    const float w1b2r = g_w1b2[r];
    const float wb0 = g_whhb2[r], wb1 = g_whhb2[NH + r], wb2 = g_whhb2[2 * NH + r];

    if (t < NS) shT[t] = times[t];
    if (t < NH) shHh[t] = (f16)0.f;
    float h = 0.f;  // fp32 h carried in registers (identical across the quad)
    __syncthreads();

    // gx double-buffer: step si's values loaded one iteration ahead.
    float gxr = 0.f, gxz = 0.f, gxn = 0.f;
    if (use_gx) {
        const float* g = gx + ((size_t)(NS - 1) * NB + b) * NG;
        gxr = g[r]; gxz = g[NH + r]; gxn = g[2 * NH + r];
    }

    for (int si = 0; si < NS; ++si) {
        const int seq = NS - 1 - si;
        const float dt = (si == 0) ? 0.f : (shT[seq] - shT[seq + 1]);
        const float dts = 0.5f * dt;  // substep dt (N_SUB=2)
        const float a2 = 0.5f * dts;
        const float a6 = dts * (1.f / 6.f);

        // issue NEXT step's gx loads now (vmcnt NOT drained by sync_lds, so
        // these stay in flight under the whole step's 9 stages).
        float gnr = 0.f, gnz = 0.f, gnn = 0.f;
        if (use_gx) {
            const int seqn = (seq > 0) ? (seq - 1) : 0;
            const float* g = gx + ((size_t)seqn * NB + b) * NG;
            gnr = g[r]; gnz = g[NH + r]; gnn = g[2 * NH + r];
        } else {
            if (t < NI) shX[t] = x[(b * NS + seq) * NI + t];
            __syncthreads();
            if (t < NG) {
                const float* wr = W_ih + t * NI;
                float a = 0.f;
#pragma unroll
                for (int cc = 0; cc < NI; cc += 4) {
                    float4 w4 = *(const float4*)(wr + cc);
                    a = fmaf(w4.x, shX[cc + 0], a);
                    a = fmaf(w4.y, shX[cc + 1], a);
                    a = fmaf(w4.z, shX[cc + 2], a);
                    a = fmaf(w4.w, shX[cc + 3], a);
                }
                shGX[t] = a + b_ih[t];
            }
            __syncthreads();
        }

        // ======== substep A ========
        float z1a, u, S, m;
        // stage 1: z1 = W1 h + b1
        DOT1(w1p, shHh, z1a);
        z1a += b1r;
        u = fast_tanh(z1a);
        S = u;
        if (p == 0) shUh[r] = (f16)u;
        sync_lds();
        // stage 2
        DOT1(w12p, shUh, m);
        u = fast_tanh(z1a + a2 * (m + w1b2r));
        S += 2.f * u;
        if (p == 0) shUh[r] = (f16)u;
        sync_lds();
        // stage 3
        DOT1(w12p, shUh, m);
        u = fast_tanh(z1a + a2 * (m + w1b2r));
        S += 2.f * u;
        if (p == 0) shUh[r] = (f16)u;
        sync_lds();
        // stage 4 (k4 uses full dts)
        DOT1(w12p, shUh, m);
        u = fast_tanh(z1a + dts * (m + w1b2r));
        S += u;
        if (p == 0) shUh[r] = (f16)S;  // S becomes the stage-5 source
        sync_lds();
        // stage 5: hA = h + a6 W2 S + dts b2 ; z1b = z1a + a6 W12 S + dts W1b2
        float mA, mB;
        DOT2S(w2p, w12p, shUh, mA, mB);
        const float hA = h + a6 * mA + dts * b2r;
        const float z1b = z1a + a6 * mB + dts * w1b2r;
        u = fast_tanh(z1b);
        float S2 = u;
        if (p == 0) { shAh[r] = (f16)hA; shUh[r] = (f16)u; }
        sync_lds();

        // ======== substep B (+ Whh·hA folded in as pair-matvecs) ========
        float g0, g1, g2;
        // stage 6
        DOT2D(w12p, shUh, wh0p, shAh, m, g0);
        u = fast_tanh(z1b + a2 * (m + w1b2r));
        S2 += 2.f * u;
        if (p == 0) shUh[r] = (f16)u;
        sync_lds();
        // stage 7
        DOT2D(w12p, shUh, wh1p, shAh, m, g1);
        u = fast_tanh(z1b + a2 * (m + w1b2r));
        S2 += 2.f * u;
        if (p == 0) shUh[r] = (f16)u;
        sync_lds();
        // stage 8
        DOT2D(w12p, shUh, wh2p, shAh, m, g2);
        u = fast_tanh(z1b + dts * (m + w1b2r));
        S2 += u;
        if (p == 0) shUh[r] = (f16)S2;  // S2 becomes the stage-9 source
        sync_lds();
        // stage 9: 4-matvec over S2 ; GRU (computed on all lanes)
        float n0, n1, n2, n3;
        DOT4S(w2p, ws0p, ws1p, ws2p, shUh, n0, n1, n2, n3);
        const float hB = hA + a6 * n0 + dts * b2r;
        const float rh = g0 + a6 * n1 + dts * wb0 + bh0;
        const float zh = g1 + a6 * n2 + dts * wb1 + bh1;
        const float nh = g2 + a6 * n3 + dts * wb2 + bh2;
        float rx, zx, nx;
        if (use_gx) { rx = gxr; zx = gxz; nx = gxn; }
        else        { rx = shGX[r]; zx = shGX[NH + r]; nx = shGX[2 * NH + r]; }
        const float rr = fast_sig(rx + rh);
        const float zz = fast_sig(zx + zh);
        const float nn = fast_tanh(nx + rr * nh);
        h = (1.f - zz) * nn + zz * hB;
        if (p == 0) shHh[r] = (f16)h;
        // rotate gx double-buffer
        gxr = gnr; gxz = gnz; gxn = gnn;
        sync_lds();
    }

    // ---- epilogue: full-precision heads from fp32 h ----
    if (p == 0) shHf[r] = h;
    __syncthreads();
    const int sel = r >> 6;
    const int l = r & 63;
    const float* Wf = sel ? W_logvar : W_mean;
    const int c0 = 32 * p;
    float a0 = 0.f, a1 = 0.f;
#pragma unroll
    for (int jj = 0; jj < 8; jj++) {
        float4 w4 = *(const float4*)&Wf[l * NH + c0 + 4 * jj];
        float4 h4 = *(const float4*)(shHf + c0 + 4 * jj);
        a0 = fmaf(w4.x, h4.x, a0);
        a1 = fmaf(w4.y, h4.y, a1);
        a0 = fmaf(w4.z, h4.z, a0);
        a1 = fmaf(w4.w, h4.w, a1);
    }
    float acc = quad_red(a0 + a1);
    if (p == 0) {
        const float bias = sel ? b_logvar[l] : b_mean[l];
        out[sel * (NB * NL) + b * NL + l] = acc + bias;
    }
}

extern "C" void kernel_launch(void* const* d_in, const int* in_sizes, int n_in,
                              void* d_out, int out_size, void* d_ws, size_t ws_size,
                              hipStream_t stream)
{
    const float* x        = (const float*)d_in[0];
    const float* times    = (const float*)d_in[1];
    const float* W_ih     = (const float*)d_in[2];
    const float* W_hh     = (const float*)d_in[3];
    const float* b_ih     = (const float*)d_in[4];
    const float* b_hh     = (const float*)d_in[5];
    const float* W1       = (const float*)d_in[6];
    const float* b1       = (const float*)d_in[7];
    const float* W2       = (const float*)d_in[8];
    const float* b2       = (const float*)d_in[9];
    const float* W_mean   = (const float*)d_in[10];
    const float* b_mean   = (const float*)d_in[11];
    const float* W_logvar = (const float*)d_in[12];
    const float* b_logvar = (const float*)d_in[13];
    float* out = (float*)d_out;

    float* gxbuf = (float*)d_ws;
    const size_t need = (size_t)NS * NB * NG * sizeof(float);  // ~50.3 MB
    const int use_gx = (d_ws != nullptr && ws_size >= need) ? 1 : 0;

    if (use_gx) {
        gx_kernel<<<NS, 384, 0, stream>>>(x, W_ih, b_ih, gxbuf);
    }
    prep_kernel<<<512, 128, 0, stream>>>(W1, W_hh, W2, b2);
    rnn_kernel<<<NB, 512, 0, stream>>>(times, b_hh, b1, b2,
                                       W_mean, b_mean, W_logvar, b_logvar,
                                       gxbuf, x, W_ih, b_ih, use_gx, out);
}